// Round 8
// baseline (39.957 us; speedup 1.0000x reference)
//
#include <hip/hip_runtime.h>

// DynamicMaskHead: per-instance 3-layer 1x1-conv MLP over [rel_xy, feats] at
// 112x200, then AdelaiDet aligned_bilinear 2x upsample to [n,1,224,400].
// Fused single kernel; logits staged in LDS (7.4 KB), one barrier total.
//
// R8: single-pass MLP (R1's fused form: layer-1 accumulators updated directly
// from each layer-0 output channel; h0 never materialized). Register split
// learned from R2-R7: w0[80] -> SGPR pins (fits <102 budget), w1/w2/b0/b1/b2
// [89] -> VGPR pins, 1 px/iter keeps live set ~120 <= 128 cap. Deletes one
// barrier + the 28.8KB h0 fp16 LDS round-trip. R5 vs R7 proved instr count is
// NOT the current limiter; this tests the phase-serialization hypothesis.

#define IN_C   8
#define CHN    8
#define Hh     112
#define Ww     200
#define HWp    (Hh * Ww)
#define OH     224
#define OW     400
#define TY     16          // output rows per block
#define RL     9           // logit rows needed per tile (TY/2 + 1)
#define NPIX   (RL * Ww)   // 1800 logit px per tile
#define NTILES (OH / TY)   // 14
#define NPARAMS 169
#define BLK    256

// param layout per instance (169 floats):
// w0 [8][10] @0, w1 [8][8] @80, w2 [8] @144, b0 [8] @152, b1 [8] @160, b2 @168

__global__ __launch_bounds__(BLK, 4)
void dmh_fused_kernel(const float* __restrict__ feats,      // [4][8][112][200]
                      const float* __restrict__ params,     // [n][169]
                      const float* __restrict__ iloc,       // [n][2]
                      const float* __restrict__ soi_tab,    // [5]
                      const int*   __restrict__ im_inds,    // [n]
                      const int*   __restrict__ fpn_levels, // [n]
                      float* __restrict__ out)              // [n][224][400]
{
    __shared__ float lgt[RL][Ww];      // logits: 7.2 KB

    const int bid  = blockIdx.x;
    const int inst = bid / NTILES;
    const int ty   = bid - inst * NTILES;
    const int y0   = ty * TY;
    const int r_lo = (y0 > 0 ? (y0 - 1) : 0) >> 1;   // first logit row of tile
    const int tid  = threadIdx.x;

    const float* __restrict__ wp = params + inst * NPARAMS;
    const float soi    = soi_tab[fpn_levels[inst]];
    const float inv_s  = 1.0f / soi;
    const float ix     = iloc[inst * 2 + 0];
    const float iy     = iloc[inst * 2 + 1];
    const float* __restrict__ fb = feats + (size_t)im_inds[inst] * (IN_C * HWp);

    // ---- w0 -> SGPRs (80; block-uniform, FMA reads 1 SGPR legally) ----
    float w0s[80];
    #pragma unroll
    for (int i = 0; i < 80; i++) w0s[i] = wp[i];
    #pragma unroll
    for (int i = 0; i < 80; i++) asm volatile("" : "+s"(w0s[i]));

    // ---- w1, w2, b0, b1, b2 -> VGPR pins (89) ----
    float w1v[64], w2v[CHN], b0v[CHN], b1v[CHN], b2v;
    #pragma unroll
    for (int i = 0; i < 64; i++) w1v[i] = wp[80 + i];
    #pragma unroll
    for (int i = 0; i < CHN; i++) w2v[i] = wp[144 + i];
    #pragma unroll
    for (int i = 0; i < CHN; i++) b0v[i] = wp[152 + i];
    #pragma unroll
    for (int i = 0; i < CHN; i++) b1v[i] = wp[160 + i];
    b2v = wp[168];
    #pragma unroll
    for (int i = 0; i < 64; i++) asm volatile("" : "+v"(w1v[i]));
    #pragma unroll
    for (int i = 0; i < CHN; i++) asm volatile("" : "+v"(w2v[i]));
    #pragma unroll
    for (int i = 0; i < CHN; i++) asm volatile("" : "+v"(b0v[i]));
    #pragma unroll
    for (int i = 0; i < CHN; i++) asm volatile("" : "+v"(b1v[i]));
    asm volatile("" : "+v"(b2v));

    // ------------- single pass: logits for rows [r_lo, r_lo+RL) -------------
    for (int g = tid; g < NPIX; g += BLK) {
        const int rr = g / Ww;              // 0..8
        const int c  = g - rr * Ww;         // 0..199
        const int r  = r_lo + rr;           // <= 111
        const float* fp = fb + r * Ww + c;

        float fv[IN_C];
        #pragma unroll
        for (int ch = 0; ch < IN_C; ch++) fv[ch] = fp[ch * HWp];

        const float in1 = (iy - (float)(r * 8 + 4)) * inv_s;
        const float in0 = (ix - (float)(c * 8 + 4)) * inv_s;

        float h1a[CHN];
        #pragma unroll
        for (int o = 0; o < CHN; o++) h1a[o] = b1v[o];

        #pragma unroll
        for (int o = 0; o < CHN; o++) {
            float t = fmaf(w0s[o * 10 + 1], in1, b0v[o]);
            t = fmaf(w0s[o * 10 + 0], in0, t);
            #pragma unroll
            for (int i = 0; i < IN_C; i++)
                t = fmaf(w0s[o * 10 + 2 + i], fv[i], t);
            t = fmaxf(t, 0.0f);
            #pragma unroll
            for (int oo = 0; oo < CHN; oo++)
                h1a[oo] = fmaf(w1v[oo * 8 + o], t, h1a[oo]);
        }
        float r0 = b2v;
        #pragma unroll
        for (int i = 0; i < CHN; i++)
            r0 = fmaf(w2v[i], fmaxf(h1a[i], 0.0f), r0);

        lgt[rr][c] = r0;
    }
    __syncthreads();

    // ============ pass C: aligned 2x bilinear, write 16x400 tile ============
    // out[y][x] = interp[max(y-1,0)][max(x-1,0)], axis weights {1} even / {.5,.5} odd
    float* __restrict__ ob = out + (size_t)inst * (OH * OW);
    const int NQ = (TY * OW) / 4;   // 1600 groups of 4 output px
    for (int q = tid; q < NQ; q += BLK) {
        const int dy = q / (OW / 4);            // 0..15
        const int gx = q - dy * (OW / 4);       // 0..99
        const int x  = gx * 4;
        const int y  = y0 + dy;
        const int i  = (y > 0 ? y - 1 : 0);
        const int rr0 = (i >> 1) - r_lo;
        const int r1g = (i >> 1) + (i & 1);
        const int rr1 = (r1g > Hh - 1 ? Hh - 1 : r1g) - r_lo;
        const float wy1 = (i & 1) ? 0.5f : 0.0f;
        const float wy0 = 1.0f - wy1;

        const int cx  = x >> 1;                 // 0..198 (x even)
        const int cm1 = (cx > 0 ? cx - 1 : 0);
        const float a_m = lgt[rr0][cm1], a_0 = lgt[rr0][cx], a_p = lgt[rr0][cx + 1];
        const float b_m = lgt[rr1][cm1], b_0 = lgt[rr1][cx], b_p = lgt[rr1][cx + 1];
        const float Rm = wy0 * a_m + wy1 * b_m;
        const float R0 = wy0 * a_0 + wy1 * b_0;
        const float Rp = wy0 * a_p + wy1 * b_p;

        float4 o4;
        o4.x = 0.5f * (Rm + R0);   // x+0: odd j (clamped at x=0 where Rm==R0)
        o4.y = R0;                 // x+1: exact col cx
        o4.z = 0.5f * (R0 + Rp);   // x+2: odd j
        o4.w = Rp;                 // x+3: exact col cx+1
        *reinterpret_cast<float4*>(&ob[y * OW + x]) = o4;
    }
}

extern "C" void kernel_launch(void* const* d_in, const int* in_sizes, int n_in,
                              void* d_out, int out_size, void* d_ws, size_t ws_size,
                              hipStream_t stream) {
    const float* mask_feats = (const float*)d_in[0];
    const float* params     = (const float*)d_in[1];
    const float* iloc       = (const float*)d_in[2];
    const float* soi        = (const float*)d_in[3];
    const int*   im_inds    = (const int*)d_in[4];
    const int*   fpn        = (const int*)d_in[5];
    // d_in[6] = mask_feat_stride (=8), baked into the kernel constants.
    float* out = (float*)d_out;

    const int n_inst = in_sizes[4];           // 200
    dim3 grid(n_inst * NTILES);               // 2800 blocks
    dim3 block(BLK);
    hipLaunchKernelGGL(dmh_fused_kernel, grid, block, 0, stream,
                       mask_feats, params, iloc, soi, im_inds, fpn, out);
}